// Round 9
// baseline (257.981 us; speedup 1.0000x reference)
//
#include <hip/hip_runtime.h>
#include <hip/hip_bf16.h>

typedef __hip_bfloat16 bf16;
typedef __attribute__((ext_vector_type(8))) short short8;   // 8 bf16 bits (4 VGPRs)
typedef __attribute__((ext_vector_type(4))) short sh4;      // 4 bf16 bits (8 B)
typedef __attribute__((ext_vector_type(4))) float f32x4;    // MFMA C/D

// Problem constants: B=2, T=4, H=W=64, C=256, ws=8
// N = 128 windows, L = 256 tokens, C = 256, heads = 8, head_dim = 32
#define SCALE_F 0.17677669529663687f
#define LOG2E_F 1.4426950408889634f
#define EPS_F 1e-5f
#define NW_CHUNK 32                 // windows per chunk (fallback path)
#define ROWS_CHUNK (NW_CHUNK * 256)

// converted bf16 weight buffer layout (offsets in shorts)
#define OW_QKV  0
#define OW_PROJ 196608
#define OB_QKV  262144
#define OB_PROJ 262912
#define NWB     263168

__device__ __forceinline__ float b2f(bf16 v) { return __bfloat162float(v); }
__device__ __forceinline__ bf16 f2b(float v) { return __float2bfloat16(v); }
__device__ __forceinline__ short f2bs(float v) { bf16 h = f2b(v); return *(short*)&h; }
__device__ __forceinline__ float bs2f(short s) { bf16 h = *(bf16*)&s; return __bfloat162float(h); }

#if __has_builtin(__builtin_amdgcn_exp2f)
__device__ __forceinline__ float fexp2(float x) { return __builtin_amdgcn_exp2f(x); }
#else
__device__ __forceinline__ float fexp2(float x) { return exp2f(x); }
#endif
#if __has_builtin(__builtin_amdgcn_rcpf)
__device__ __forceinline__ float frcp(float x) { return __builtin_amdgcn_rcpf(x); }
#else
__device__ __forceinline__ float frcp(float x) { return 1.0f / x; }
#endif

__device__ __forceinline__ float ldin(const void* p, size_t i, int mode) {
  if (mode) return ((const float*)p)[i];
  return b2f(((const bf16*)p)[i]);
}
__device__ __forceinline__ void stout(void* p, size_t i, int mode, float v) {
  if (mode) ((float*)p)[i] = v;
  else      ((bf16*)p)[i] = f2b(v);
}
__device__ __forceinline__ float4 ldin4(const void* p, size_t i, int mode) {
  if (mode) return *(const float4*)((const float*)p + i);
  const sh4 s = *(const sh4*)((const short*)p + i);
  return make_float4(bs2f(s[0]), bs2f(s[1]), bs2f(s[2]), bs2f(s[3]));
}
__device__ __forceinline__ void stout4(void* p, size_t i, int mode, float4 v) {
  if (mode) { *(float4*)((float*)p + i) = v; }
  else {
    sh4 s; s[0] = f2bs(v.x); s[1] = f2bs(v.y); s[2] = f2bs(v.z); s[3] = f2bs(v.w);
    *(sh4*)((short*)p + i) = s;
  }
}

// Inline dtype probe: every block computes mode locally from x[0..1023].
__device__ __forceinline__ int probe_mode(const float* xf, int tid) {
  __shared__ int s_cnt;
  if (tid == 0) s_cnt = 0;
  __syncthreads();
  int bad = 0;
#pragma unroll
  for (int i = 0; i < 4; ++i) {
    const float v = xf[tid * 4 + i];
    if (!(fabsf(v) < 1e20f)) bad++;
  }
  if (bad) atomicAdd(&s_cnt, bad);
  __syncthreads();
  return (s_cnt < 8) ? 1 : 0;
}

// async global->LDS DMA, 16 B/lane; LDS dst wave-uniform, HW writes lane l's
// 16 B at dst + l*16. Global src is per-lane.
__device__ __forceinline__ void gld16(void* lds, const void* g) {
  __builtin_amdgcn_global_load_lds(
      (const __attribute__((address_space(1))) unsigned int*)g,
      (__attribute__((address_space(3))) unsigned int*)lds, 16, 0, 0);
}

// ---------------------------------------------------------------------------
// Kernel 1: gather + LayerNorm + merged weight cast (R8-passing, unchanged).
// ---------------------------------------------------------------------------
__global__ __launch_bounds__(256) void k_ln(const void* __restrict__ x,
                                            const void* __restrict__ gamma,
                                            const void* __restrict__ beta,
                                            bf16* __restrict__ xn,
                                            const void* __restrict__ w1,
                                            const void* __restrict__ w2,
                                            const void* __restrict__ b1,
                                            const void* __restrict__ b2,
                                            short* __restrict__ wbuf) {
  const int tid = threadIdx.x;
  const int mode = probe_mode((const float*)x, tid);

  {
    const int base = (blockIdx.x * 256 + tid) * 2;
#pragma unroll
    for (int e = 0; e < 2; ++e) {
      const int i = base + e;
      float v;
      if (i < OW_PROJ)      v = ldin(w1, i, mode);
      else if (i < OB_QKV)  v = ldin(w2, i - OW_PROJ, mode);
      else if (i < OB_PROJ) v = ldin(b1, i - OB_QKV, mode);
      else                  v = ldin(b2, i - OB_PROJ, mode);
      wbuf[i] = f2bs(v);
    }
    if (blockIdx.x == 0) {  // tail: 262144..NWB-1 (1024 elems)
#pragma unroll
      for (int e = 0; e < 4; ++e) {
        const int i = 262144 + tid * 4 + e;
        float v;
        if (i < OB_PROJ) v = ldin(b1, i - OB_QKV, mode);
        else             v = ldin(b2, i - OB_PROJ, mode);
        wbuf[i] = f2bs(v);
      }
    }
  }

  const int bt = blockIdx.x >> 6;      // 0..7
  const int h  = blockIdx.x & 63;      // 0..63
  const int cl = tid >> 4;             // 0..15
  const int wi = tid & 15;             // 0..15

  __shared__ short sX[256][68];
  __shared__ float sred[16][65];
  __shared__ float sqred[16][65];
  __shared__ float smu[64], srs[64];
  __shared__ float sGm[256], sBt[256];

  sGm[tid] = ldin(gamma, tid, mode);
  sBt[tid] = ldin(beta, tid, mode);

  const size_t gbase = (size_t)bt * 1048576 + (size_t)h * 64 + wi * 4;
  float s4[4] = {0.f, 0.f, 0.f, 0.f}, q4[4] = {0.f, 0.f, 0.f, 0.f};
  for (int c0 = 0; c0 < 256; c0 += 16) {
    const int c = c0 + cl;
    const float4 v = ldin4(x, gbase + (size_t)c * 4096, mode);
    s4[0] += v.x; q4[0] += v.x * v.x;
    s4[1] += v.y; q4[1] += v.y * v.y;
    s4[2] += v.z; q4[2] += v.z * v.z;
    s4[3] += v.w; q4[3] += v.w * v.w;
    sh4 b;
    b[0] = f2bs(v.x); b[1] = f2bs(v.y); b[2] = f2bs(v.z); b[3] = f2bs(v.w);
    *(sh4*)&sX[c][wi * 4] = b;
  }
#pragma unroll
  for (int k = 0; k < 4; ++k) {
    sred[cl][wi * 4 + k] = s4[k];
    sqred[cl][wi * 4 + k] = q4[k];
  }
  __syncthreads();
  if (tid < 64) {
    float a = 0.f, q = 0.f;
#pragma unroll
    for (int g = 0; g < 16; ++g) { a += sred[g][tid]; q += sqred[g][tid]; }
    const float mu = a * (1.0f / 256.0f);
    const float var = fmaxf(q * (1.0f / 256.0f) - mu * mu, 0.0f);
    smu[tid] = mu; srs[tid] = rsqrtf(var + EPS_F);
  }
  __syncthreads();

  // Phase 2: thread -> one token (w = tid>>2), c-range (tid&3)*64..+63.
  {
    const int wtok = tid >> 2;           // 0..63
    const int iw2 = wtok >> 3, s2 = wtok & 7;
    const int cg = (tid & 3) * 64;
    const float mu2 = smu[wtok], rs2 = srs[wtok];
    const int n2 = (bt >> 2) * 64 + (h >> 3) * 8 + iw2;
    const int l2 = (bt & 3) * 64 + (h & 7) * 8 + s2;
    short* xns = (short*)xn;
    const size_t addr = ((size_t)n2 * 256 + l2) * 256 + cg;
#pragma unroll
    for (int k = 0; k < 64; k += 4) {
      sh4 o;
#pragma unroll
      for (int e = 0; e < 4; ++e) {
        const int c = cg + k + e;
        const float v = bs2f(sX[c][wtok]);
        o[e] = f2bs((v - mu2) * rs2 * sGm[c] + sBt[c]);
      }
      *(sh4*)&xns[addr + k] = o;
    }
  }
}

// ---------------------------------------------------------------------------
// Kernel 2: MFMA qkv GEMM (R8-passing, unchanged; slab pitch 64, 5 blk/CU).
// ---------------------------------------------------------------------------
__global__ __launch_bounds__(256) void k_qkv(const bf16* __restrict__ A,
                                             const short* __restrict__ wb,
                                             bf16* __restrict__ out,
                                             int row_base) {
  __shared__ short smem[2 * 128 * 64];   // 32768 B
  short* sA = smem;
  short* sB = smem + 128 * 64;
  const int row0 = blockIdx.x * 128;
  const int col0 = blockIdx.y * 128;
  const int tid = threadIdx.x;
  const int wid = tid >> 6, lane = tid & 63;
  const int wy = wid >> 1, wx = wid & 1;
  const int l15 = lane & 15, quad = lane >> 4;
  const short* Ab = (const short*)A;

  const int lr = lane >> 3;
  const int swc = (lane & 7) ^ lr;

  f32x4 acc[4][4];
#pragma unroll
  for (int i = 0; i < 4; ++i)
#pragma unroll
    for (int j = 0; j < 4; ++j) acc[i][j] = (f32x4){0.f, 0.f, 0.f, 0.f};

  for (int k0 = 0; k0 < 256; k0 += 64) {
    if (k0) __syncthreads();
#pragma unroll
    for (int it = 0; it < 4; ++it) {
      const int rbase = wid * 32 + it * 8;
      gld16(sA + rbase * 64,
            Ab + (size_t)(row_base + row0 + rbase + lr) * 256 + k0 + swc * 8);
      gld16(sB + rbase * 64,
            wb + (size_t)(col0 + rbase + lr) * 256 + k0 + swc * 8);
    }
    asm volatile("s_waitcnt vmcnt(0)" ::: "memory");
    __syncthreads();
#pragma unroll
    for (int kk = 0; kk < 64; kk += 32) {
      const int ck = kk >> 3;
      short8 af[4], bfv[4];
#pragma unroll
      for (int i = 0; i < 4; ++i) {
        const int ar = wy * 64 + i * 16 + l15;
        af[i] = *(const short8*)(sA + ar * 64 + (((quad + ck) ^ (ar & 7)) * 8));
      }
#pragma unroll
      for (int j = 0; j < 4; ++j) {
        const int br = wx * 64 + j * 16 + l15;
        bfv[j] = *(const short8*)(sB + br * 64 + (((quad + ck) ^ (br & 7)) * 8));
      }
#pragma unroll
      for (int i = 0; i < 4; ++i)
#pragma unroll
        for (int j = 0; j < 4; ++j)
          acc[i][j] = __builtin_amdgcn_mfma_f32_16x16x32_bf16(af[i], bfv[j], acc[i][j], 0, 0, 0);
    }
  }

  __syncthreads();
  short* slab = smem + wid * (64 * 64);   // 64 rows x pitch 64, fits exactly
#pragma unroll
  for (int j = 0; j < 4; ++j) {
    const int col = col0 + wx * 64 + j * 16 + l15;
    const float bj = bs2f(wb[OB_QKV + col]);
#pragma unroll
    for (int i = 0; i < 4; ++i)
#pragma unroll
      for (int r = 0; r < 4; ++r)
        slab[(i * 16 + quad * 4 + r) * 64 + j * 16 + l15] = f2bs(acc[i][j][r] + bj);
  }
  {
    const int srow = lane >> 3;
    const int scol = (lane & 7) * 8;
    short* og = (short*)out;
#pragma unroll
    for (int it = 0; it < 8; ++it) {
      const int rloc = it * 8 + srow;
      short8 v = *(const short8*)&slab[rloc * 64 + scol];
      *(short8*)&og[(size_t)(row0 + wy * 64 + rloc) * 768 + col0 + wx * 64 + scol] = v;
    }
  }
}

// ---------------------------------------------------------------------------
// Kernel 3: MFMA attention. This round: 2-deep lt pipeline via
// #pragma unroll 2 (T15 mechanism — lt+1's QK^T MFMA + exp chain overlap
// lt's PV tail; the loop boundary was the only blocker after R5 removed all
// intra-loop barriers). All indices become compile-time under unroll (rule
// #20 safe). __launch_bounds__(256,4) pins VGPR <= 128 so occupancy holds
// at 4 blocks/CU (LDS caps there anyway). sP WAR across lt is enforced by
// compiler alias analysis (same addresses -> ordered), which serializes sP
// reuse but leaves QK^T/exp free to overlap.
// ---------------------------------------------------------------------------
__global__ __launch_bounds__(256, 4) void k_attn(const bf16* __restrict__ qkv,
                                                 bf16* __restrict__ aout,
                                                 int n_base, int nw_mask, int nw_shift) {
  const int n_loc = blockIdx.x & nw_mask, hh = blockIdx.x >> nw_shift;
  const int n_glob = n_base + n_loc;
  __shared__ short sK[256][32];      // 16 KB, linear, DMA-staged
  __shared__ short sVt[32][256];     // 16 KB, chunk-XOR key row&7
  __shared__ short sP[4][16][64];    // 8 KB, chunk-XOR key l15&7
  const int tid = threadIdx.x;
  const int wid = tid >> 6, lane = tid & 63;
  const int l15 = lane & 15, quad = lane >> 4;
  const int l7 = l15 & 7;
  const short* qg = (const short*)qkv;
  const size_t base = (size_t)n_loc * 256 * 768 + hh * 32;

  // K staging via global_load_lds: 4 instrs/wave, 16 rows x 32 shorts each.
#pragma unroll
  for (int it = 0; it < 4; ++it) {
    const int rbase = wid * 64 + it * 16;
    gld16(&sK[rbase][0],
          qg + base + (size_t)(rbase + (lane >> 2)) * 768 + 256 + (lane & 3) * 8);
  }
  // V transpose staging (manual scatter), physical chunk = (m>>3) ^ (d&7).
  for (int c = tid; c < 1024; c += 256) {
    const int m = c >> 2, d0 = (c & 3) * 8;
    short8 vv = *(const short8*)(qg + base + (size_t)m * 768 + 512 + d0);
#pragma unroll
    for (int j = 0; j < 8; ++j)
      sVt[d0 + j][(((m >> 3) ^ j) << 3) | (m & 7)] = vv[j];
  }
  asm volatile("s_waitcnt vmcnt(0)" ::: "memory");
  __syncthreads();

  const int R0 = wid * 64;
  const float esc = SCALE_F * LOG2E_F;

#pragma unroll 2
  for (int lt = 0; lt < 4; ++lt) {
    const int lrow = R0 + lt * 16;
    const short8 qf = *(const short8*)(qg + base + (size_t)(lrow + l15) * 768 + quad * 8);

    // QK^T swapped: sacc[t][r] = S[qrow=l15][kv = t*16 + quad*4 + r].
    f32x4 sacc[16];
    __builtin_amdgcn_s_setprio(1);
#pragma unroll
    for (int t = 0; t < 16; ++t) {
      sacc[t] = (f32x4){0.f, 0.f, 0.f, 0.f};
      const short8 kf = *(const short8*)&sK[t * 16 + l15][quad * 8];
      sacc[t] = __builtin_amdgcn_mfma_f32_16x16x32_bf16(kf, qf, sacc[t], 0, 0, 0);
    }
    __builtin_amdgcn_s_setprio(0);

    float sum = 0.f;
    f32x4 oacc[2] = {(f32x4){0.f, 0.f, 0.f, 0.f}, (f32x4){0.f, 0.f, 0.f, 0.f}};

#pragma unroll
    for (int ph = 0; ph < 4; ++ph) {
      // exp + pack + write: 4 t-tiles, one b64 (sh4) write each.
#pragma unroll
      for (int tp = 0; tp < 4; ++tp) {
        const int t = ph * 4 + tp;
        const float p0 = fexp2(sacc[t][0] * esc);
        const float p1 = fexp2(sacc[t][1] * esc);
        const float p2 = fexp2(sacc[t][2] * esc);
        const float p3 = fexp2(sacc[t][3] * esc);
        sum += (p0 + p1) + (p2 + p3);
        sh4 w;
        w[0] = f2bs(p0); w[1] = f2bs(p1); w[2] = f2bs(p2); w[3] = f2bs(p3);
        const int chunk = tp * 2 + (quad >> 1);           // local kv chunk 0..7
        *(sh4*)&sP[wid][l15][((chunk ^ l7) << 3) | ((quad & 1) * 4)] = w;
      }
      __builtin_amdgcn_s_setprio(1);
#pragma unroll
      for (int kk = 0; kk < 2; ++kk) {
        const int pphys = (kk * 4 + quad) ^ l7;           // phys chunk, row=l15
        const short8 pf = *(const short8*)&sP[wid][l15][pphys * 8];
#pragma unroll
        for (int dt = 0; dt < 2; ++dt) {
          const int vrow = dt * 16 + l15;
          const int cch = ph * 8 + kk * 4 + quad;         // global kv chunk
          const short8 vf = *(const short8*)&sVt[vrow][((cch ^ (vrow & 7)) * 8)];
          // A=Vt (rows=d), B=P (rows=q) -> O^T: row=d, col=q.
          oacc[dt] = __builtin_amdgcn_mfma_f32_16x16x32_bf16(vf, pf, oacc[dt], 0, 0, 0);
        }
      }
      __builtin_amdgcn_s_setprio(0);
    }

    // row-sum finish: reduce across quads (same l15 = same q-row = this
    // lane's output column). No redistribution needed.
    sum += __shfl_xor(sum, 16, 64);
    sum += __shfl_xor(sum, 32, 64);
    const float inv = frcp(sum);

    // Direct O store: lane (l15,quad) holds O[q=l15][d=dt*16+quad*4+r].
    {
      short* og = (short*)aout;
      const size_t obase =
          ((size_t)n_glob * 256 + lrow + l15) * 256 + hh * 32 + quad * 4;
#pragma unroll
      for (int dt = 0; dt < 2; ++dt) {
        sh4 w;
#pragma unroll
        for (int r = 0; r < 4; ++r) w[r] = f2bs(oacc[dt][r] * inv);
        *(sh4*)&og[obase + dt * 16] = w;
      }
    }
  }
}

// ---------------------------------------------------------------------------
// Kernel 4a: proj GEMM only -> tmp[token][c] (R8-passing, unchanged).
// ---------------------------------------------------------------------------
__global__ __launch_bounds__(256) void k_proj_g(const bf16* __restrict__ A,
                                                const short* __restrict__ wb,
                                                bf16* __restrict__ out) {
  __shared__ short smem[2 * 128 * 64];
  short* sA = smem;
  short* sB = smem + 128 * 64;
  const int row0 = blockIdx.x * 128;
  const int col0 = blockIdx.y * 128;
  const int tid = threadIdx.x;
  const int wid = tid >> 6, lane = tid & 63;
  const int wy = wid >> 1, wx = wid & 1;
  const int l15 = lane & 15, quad = lane >> 4;
  const short* Ab = (const short*)A;

  const int lr = lane >> 3;
  const int swc = (lane & 7) ^ lr;

  f32x4 acc[4][4];
#pragma unroll
  for (int i = 0; i < 4; ++i)
#pragma unroll
    for (int j = 0; j < 4; ++j) acc[i][j] = (f32x4){0.f, 0.f, 0.f, 0.f};

  for (int k0 = 0; k0 < 256; k0 += 64) {
    if (k0) __syncthreads();
#pragma unroll
    for (int it = 0; it < 4; ++it) {
      const int rbase = wid * 32 + it * 8;
      gld16(sA + rbase * 64,
            Ab + (size_t)(row0 + rbase + lr) * 256 + k0 + swc * 8);
      gld16(sB + rbase * 64,
            wb + OW_PROJ + (size_t)(col0 + rbase + lr) * 256 + k0 + swc * 8);
    }
    asm volatile("s_waitcnt vmcnt(0)" ::: "memory");
    __syncthreads();
#pragma unroll
    for (int kk = 0; kk < 64; kk += 32) {
      const int ck = kk >> 3;
      short8 af[4], bfv[4];
#pragma unroll
      for (int i = 0; i < 4; ++i) {
        const int ar = wy * 64 + i * 16 + l15;
        af[i] = *(const short8*)(sA + ar * 64 + (((quad + ck) ^ (ar & 7)) * 8));
      }
#pragma unroll
      for (int j = 0; j < 4; ++j) {
        const int br = wx * 64 + j * 16 + l15;
        bfv[j] = *(const short8*)(sB + br * 64 + (((quad + ck) ^ (br & 7)) * 8));
      }
#pragma unroll
      for (int i = 0; i < 4; ++i)
#pragma unroll
        for (int j = 0; j < 4; ++j)
          acc[i][j] = __builtin_amdgcn_mfma_f32_16x16x32_bf16(af[i], bfv[j], acc[i][j], 0, 0, 0);
    }
  }

  __syncthreads();
  short* slab = smem + wid * (64 * 64);   // pitch 64, fits exactly
#pragma unroll
  for (int j = 0; j < 4; ++j) {
    const int col = col0 + wx * 64 + j * 16 + l15;
    const float bj = bs2f(wb[OB_PROJ + col]);
#pragma unroll
    for (int i = 0; i < 4; ++i)
#pragma unroll
      for (int r = 0; r < 4; ++r)
        slab[(i * 16 + quad * 4 + r) * 64 + j * 16 + l15] = f2bs(acc[i][j][r] + bj);
  }
  {
    const int srow = lane >> 3;
    const int scol = (lane & 7) * 8;
    short* og = (short*)out;
#pragma unroll
    for (int it = 0; it < 8; ++it) {
      const int rloc = it * 8 + srow;
      short8 v = *(const short8*)&slab[rloc * 64 + scol];
      *(short8*)&og[(size_t)(row0 + wy * 64 + rloc) * 256 + col0 + wx * 64 + scol] = v;
    }
  }
}

// ---------------------------------------------------------------------------
// Kernel 4b: residual add + un-window, fully coalesced both sides (R8).
// ---------------------------------------------------------------------------
__global__ __launch_bounds__(256) void k_add(const bf16* __restrict__ tmp,
                                             const void* __restrict__ x,
                                             void* __restrict__ out) {
  const int tid = threadIdx.x;
  const int mode = probe_mode((const float*)x, tid);
  const int bt = blockIdx.x >> 6;      // 0..7
  const int h  = blockIdx.x & 63;      // 0..63

  __shared__ short sT2[256][68];       // [c][w], w-group swizzled

  const int n_b = (bt >> 2) * 64 + (h >> 3) * 8;
  const int l0  = (bt & 3) * 64 + (h & 7) * 8;
  const short* tg = (const short*)tmp;

#pragma unroll
  for (int i = 0; i < 8; ++i) {
    const int id = i * 256 + tid;
    const int w = id >> 5, c8 = (id & 31) * 8;
    const int row = (n_b + (w >> 3)) * 256 + l0 + (w & 7);
    const short8 v = *(const short8*)(tg + (size_t)row * 256 + c8);
    const int wg = ((w >> 2) ^ ((id & 31) & 15)) * 4 + (w & 3);
#pragma unroll
    for (int j = 0; j < 8; ++j) sT2[c8 + j][wg] = v[j];
  }
  __syncthreads();

  const int cl = tid >> 4;             // 0..15
  const int wi = tid & 15;             // 0..15
  const size_t gb = (size_t)bt * 1048576 + (size_t)h * 64 + wi * 4;
  for (int c0 = 0; c0 < 256; c0 += 16) {
    const int c = c0 + cl;
    const int k15 = (c >> 3) & 15;
    const sh4 pv = *(const sh4*)&sT2[c][((wi ^ k15) & 15) * 4];
    const size_t gaddr = gb + (size_t)c * 4096;
    const float4 xv = ldin4(x, gaddr, mode);
    float4 o;
    o.x = xv.x + bs2f(pv[0]);
    o.y = xv.y + bs2f(pv[1]);
    o.z = xv.z + bs2f(pv[2]);
    o.w = xv.w + bs2f(pv[3]);
    stout4(out, gaddr, mode, o);
  }
}

// ---------------------------------------------------------------------------
// Kernel 4 (fallback path only): MFMA proj GEMM + scatter epilogue.
// ---------------------------------------------------------------------------
__global__ __launch_bounds__(256) void k_proj(const bf16* __restrict__ A,
                                              const short* __restrict__ wb,
                                              const void* __restrict__ x,
                                              void* __restrict__ out) {
  const int tid = threadIdx.x;
  const int mode = probe_mode((const float*)x, tid);
  __shared__ short smem[2 * 128 * 64];
  __shared__ float sT[4][16][17];
  short* sA = smem;
  short* sB = smem + 128 * 64;
  const int row0 = blockIdx.x * 128;
  const int col0 = blockIdx.y * 128;
  const int wid = tid >> 6, lane = tid & 63;
  const int wy = wid >> 1, wx = wid & 1;
  const int l15 = lane & 15, quad = lane >> 4;
  const short* Ab = (const short*)A;

  const int lr = lane >> 3;
  const int swc = (lane & 7) ^ lr;

  f32x4 acc[4][4];
#pragma unroll
  for (int i = 0; i < 4; ++i)
#pragma unroll
    for (int j = 0; j < 4; ++j) acc[i][j] = (f32x4){0.f, 0.f, 0.f, 0.f};

  for (int k0 = 0; k0 < 256; k0 += 64) {
    if (k0) __syncthreads();
#pragma unroll
    for (int it = 0; it < 4; ++it) {
      const int rbase = wid * 32 + it * 8;
      gld16(sA + rbase * 64,
            Ab + (size_t)(row0 + rbase + lr) * 256 + k0 + swc * 8);
      gld16(sB + rbase * 64,
            wb + OW_PROJ + (size_t)(col0 + rbase + lr) * 256 + k0 + swc * 8);
    }
    asm volatile("s_waitcnt vmcnt(0)" ::: "memory");
    __syncthreads();
#pragma unroll
    for (int kk = 0; kk < 64; kk += 32) {
      const int ck = kk >> 3;
      short8 af[4], bfv[4];
#pragma unroll
      for (int i = 0; i < 4; ++i) {
        const int ar = wy * 64 + i * 16 + l15;
        af[i] = *(const short8*)(sA + ar * 64 + (((quad + ck) ^ (ar & 7)) * 8));
      }
#pragma unroll
      for (int j = 0; j < 4; ++j) {
        const int br = wx * 64 + j * 16 + l15;
        bfv[j] = *(const short8*)(sB + br * 64 + (((quad + ck) ^ (br & 7)) * 8));
      }
#pragma unroll
      for (int i = 0; i < 4; ++i)
#pragma unroll
        for (int j = 0; j < 4; ++j)
          acc[i][j] = __builtin_amdgcn_mfma_f32_16x16x32_bf16(af[i], bfv[j], acc[i][j], 0, 0, 0);
    }
  }

#pragma unroll
  for (int i = 0; i < 4; ++i) {
#pragma unroll
    for (int j = 0; j < 4; ++j) {
#pragma unroll
      for (int r = 0; r < 4; ++r)
        sT[wid][quad * 4 + r][l15] = acc[i][j][r];
      asm volatile("s_waitcnt lgkmcnt(0)" ::: "memory");
#pragma unroll
      for (int r2 = 0; r2 < 4; ++r2) {
        const float v = sT[wid][l15][quad * 4 + r2];
        const int row = row0 + wy * 64 + i * 16 + l15;
        const int c   = col0 + wx * 64 + j * 16 + quad * 4 + r2;
        const int n = row >> 8, l = row & 255;
        const int b = n >> 6, ih = (n >> 3) & 7, iw = n & 7;
        const int tt = l >> 6, rr = (l >> 3) & 7, ss = l & 7;
        const int btl = b * 4 + tt;
        const size_t gaddr = (size_t)btl * 1048576 + (size_t)c * 4096 +
                             (ih * 8 + rr) * 64 + iw * 8 + ss;
        const float o = v + bs2f(wb[OB_PROJ + c]) + ldin(x, gaddr, mode);
        stout(out, gaddr, mode, o);
      }
      asm volatile("s_waitcnt lgkmcnt(0)" ::: "memory");
    }
  }
}

// ---------------------------------------------------------------------------
extern "C" void kernel_launch(void* const* d_in, const int* in_sizes, int n_in,
                              void* d_out, int out_size, void* d_ws, size_t ws_size,
                              hipStream_t stream) {
  (void)in_sizes; (void)n_in; (void)out_size;
  const void* x      = d_in[0];
  const void* w_qkv  = d_in[1];
  const void* b_qkv  = d_in[2];
  const void* w_proj = d_in[3];
  const void* b_proj = d_in[4];
  const void* gamma  = d_in[5];
  const void* beta   = d_in[6];

  char* ws = (char*)d_ws;
  short* wbuf  = (short*)(ws + 1024);                       // NWB*2 = 526336 B
  bf16* xnbuf  = (bf16*)(ws + 1024 + 526336);               // 16 MiB
  bf16* qkvb   = (bf16*)(ws + 1024 + 526336 + 16777216);    // full 48 MiB / chunk 12.6 MiB

  const size_t need_full = 1024 + 526336 + 16777216 + (size_t)32768 * 768 * 2;

  hipLaunchKernelGGL(k_ln, dim3(512), dim3(256), 0, stream, x, gamma, beta, xnbuf,
                     w_qkv, w_proj, b_qkv, b_proj, wbuf);

  if (ws_size >= need_full) {
    hipLaunchKernelGGL(k_qkv, dim3(256, 6), dim3(256), 0, stream,
                       xnbuf, wbuf, qkvb, 0);
    hipLaunchKernelGGL(k_attn, dim3(1024), dim3(256), 0, stream,
                       qkvb, xnbuf, 0, 127, 7);
    bf16* tmpb = qkvb;
    hipLaunchKernelGGL(k_proj_g, dim3(256, 2), dim3(256), 0, stream,
                       xnbuf, wbuf, tmpb);
    hipLaunchKernelGGL(k_add, dim3(512), dim3(256), 0, stream,
                       tmpb, x, d_out);
  } else {
    for (int c = 0; c < 4; ++c) {
      hipLaunchKernelGGL(k_qkv, dim3(64, 6), dim3(256), 0, stream,
                         xnbuf, wbuf, qkvb, c * ROWS_CHUNK);
      hipLaunchKernelGGL(k_attn, dim3(NW_CHUNK * 8), dim3(256), 0, stream,
                         qkvb, xnbuf, c * NW_CHUNK, NW_CHUNK - 1, 5);
    }
    hipLaunchKernelGGL(k_proj, dim3(256, 2), dim3(256), 0, stream,
                       xnbuf, wbuf, x, d_out);
  }
}

// Round 10
// 169.744 us; speedup vs baseline: 1.5198x; 1.5198x over previous
//
#include <hip/hip_runtime.h>
#include <hip/hip_bf16.h>

typedef __hip_bfloat16 bf16;
typedef __attribute__((ext_vector_type(8))) short short8;   // 8 bf16 bits (4 VGPRs)
typedef __attribute__((ext_vector_type(4))) short sh4;      // 4 bf16 bits (8 B)
typedef __attribute__((ext_vector_type(4))) float f32x4;    // MFMA C/D

// Problem constants: B=2, T=4, H=W=64, C=256, ws=8
// N = 128 windows, L = 256 tokens, C = 256, heads = 8, head_dim = 32
#define SCALE_F 0.17677669529663687f
#define LOG2E_F 1.4426950408889634f
#define EPS_F 1e-5f
#define NW_CHUNK 32                 // windows per chunk (fallback path)
#define ROWS_CHUNK (NW_CHUNK * 256)

// converted bf16 weight buffer layout (offsets in shorts)
#define OW_QKV  0
#define OW_PROJ 196608
#define OB_QKV  262144
#define OB_PROJ 262912
#define NWB     263168

__device__ __forceinline__ float b2f(bf16 v) { return __bfloat162float(v); }
__device__ __forceinline__ bf16 f2b(float v) { return __float2bfloat16(v); }
__device__ __forceinline__ short f2bs(float v) { bf16 h = f2b(v); return *(short*)&h; }
__device__ __forceinline__ float bs2f(short s) { bf16 h = *(bf16*)&s; return __bfloat162float(h); }

#if __has_builtin(__builtin_amdgcn_exp2f)
__device__ __forceinline__ float fexp2(float x) { return __builtin_amdgcn_exp2f(x); }
#else
__device__ __forceinline__ float fexp2(float x) { return exp2f(x); }
#endif
#if __has_builtin(__builtin_amdgcn_rcpf)
__device__ __forceinline__ float frcp(float x) { return __builtin_amdgcn_rcpf(x); }
#else
__device__ __forceinline__ float frcp(float x) { return 1.0f / x; }
#endif

__device__ __forceinline__ float ldin(const void* p, size_t i, int mode) {
  if (mode) return ((const float*)p)[i];
  return b2f(((const bf16*)p)[i]);
}
__device__ __forceinline__ void stout(void* p, size_t i, int mode, float v) {
  if (mode) ((float*)p)[i] = v;
  else      ((bf16*)p)[i] = f2b(v);
}
__device__ __forceinline__ float4 ldin4(const void* p, size_t i, int mode) {
  if (mode) return *(const float4*)((const float*)p + i);
  const sh4 s = *(const sh4*)((const short*)p + i);
  return make_float4(bs2f(s[0]), bs2f(s[1]), bs2f(s[2]), bs2f(s[3]));
}
__device__ __forceinline__ void stout4(void* p, size_t i, int mode, float4 v) {
  if (mode) { *(float4*)((float*)p + i) = v; }
  else {
    sh4 s; s[0] = f2bs(v.x); s[1] = f2bs(v.y); s[2] = f2bs(v.z); s[3] = f2bs(v.w);
    *(sh4*)((short*)p + i) = s;
  }
}

// Inline dtype probe: every block computes mode locally from x[0..1023].
__device__ __forceinline__ int probe_mode(const float* xf, int tid) {
  __shared__ int s_cnt;
  if (tid == 0) s_cnt = 0;
  __syncthreads();
  int bad = 0;
#pragma unroll
  for (int i = 0; i < 4; ++i) {
    const float v = xf[tid * 4 + i];
    if (!(fabsf(v) < 1e20f)) bad++;
  }
  if (bad) atomicAdd(&s_cnt, bad);
  __syncthreads();
  return (s_cnt < 8) ? 1 : 0;
}

// async global->LDS DMA, 16 B/lane; LDS dst wave-uniform, HW writes lane l's
// 16 B at dst + l*16. Global src is per-lane.
__device__ __forceinline__ void gld16(void* lds, const void* g) {
  __builtin_amdgcn_global_load_lds(
      (const __attribute__((address_space(1))) unsigned int*)g,
      (__attribute__((address_space(3))) unsigned int*)lds, 16, 0, 0);
}

// ---------------------------------------------------------------------------
// Kernel 1: gather + LayerNorm + merged weight cast (R8-passing, unchanged).
// ---------------------------------------------------------------------------
__global__ __launch_bounds__(256) void k_ln(const void* __restrict__ x,
                                            const void* __restrict__ gamma,
                                            const void* __restrict__ beta,
                                            bf16* __restrict__ xn,
                                            const void* __restrict__ w1,
                                            const void* __restrict__ w2,
                                            const void* __restrict__ b1,
                                            const void* __restrict__ b2,
                                            short* __restrict__ wbuf) {
  const int tid = threadIdx.x;
  const int mode = probe_mode((const float*)x, tid);

  {
    const int base = (blockIdx.x * 256 + tid) * 2;
#pragma unroll
    for (int e = 0; e < 2; ++e) {
      const int i = base + e;
      float v;
      if (i < OW_PROJ)      v = ldin(w1, i, mode);
      else if (i < OB_QKV)  v = ldin(w2, i - OW_PROJ, mode);
      else if (i < OB_PROJ) v = ldin(b1, i - OB_QKV, mode);
      else                  v = ldin(b2, i - OB_PROJ, mode);
      wbuf[i] = f2bs(v);
    }
    if (blockIdx.x == 0) {  // tail: 262144..NWB-1 (1024 elems)
#pragma unroll
      for (int e = 0; e < 4; ++e) {
        const int i = 262144 + tid * 4 + e;
        float v;
        if (i < OB_PROJ) v = ldin(b1, i - OB_QKV, mode);
        else             v = ldin(b2, i - OB_PROJ, mode);
        wbuf[i] = f2bs(v);
      }
    }
  }

  const int bt = blockIdx.x >> 6;      // 0..7
  const int h  = blockIdx.x & 63;      // 0..63
  const int cl = tid >> 4;             // 0..15
  const int wi = tid & 15;             // 0..15

  __shared__ short sX[256][68];
  __shared__ float sred[16][65];
  __shared__ float sqred[16][65];
  __shared__ float smu[64], srs[64];
  __shared__ float sGm[256], sBt[256];

  sGm[tid] = ldin(gamma, tid, mode);
  sBt[tid] = ldin(beta, tid, mode);

  const size_t gbase = (size_t)bt * 1048576 + (size_t)h * 64 + wi * 4;
  float s4[4] = {0.f, 0.f, 0.f, 0.f}, q4[4] = {0.f, 0.f, 0.f, 0.f};
  for (int c0 = 0; c0 < 256; c0 += 16) {
    const int c = c0 + cl;
    const float4 v = ldin4(x, gbase + (size_t)c * 4096, mode);
    s4[0] += v.x; q4[0] += v.x * v.x;
    s4[1] += v.y; q4[1] += v.y * v.y;
    s4[2] += v.z; q4[2] += v.z * v.z;
    s4[3] += v.w; q4[3] += v.w * v.w;
    sh4 b;
    b[0] = f2bs(v.x); b[1] = f2bs(v.y); b[2] = f2bs(v.z); b[3] = f2bs(v.w);
    *(sh4*)&sX[c][wi * 4] = b;
  }
#pragma unroll
  for (int k = 0; k < 4; ++k) {
    sred[cl][wi * 4 + k] = s4[k];
    sqred[cl][wi * 4 + k] = q4[k];
  }
  __syncthreads();
  if (tid < 64) {
    float a = 0.f, q = 0.f;
#pragma unroll
    for (int g = 0; g < 16; ++g) { a += sred[g][tid]; q += sqred[g][tid]; }
    const float mu = a * (1.0f / 256.0f);
    const float var = fmaxf(q * (1.0f / 256.0f) - mu * mu, 0.0f);
    smu[tid] = mu; srs[tid] = rsqrtf(var + EPS_F);
  }
  __syncthreads();

  // Phase 2: thread -> one token (w = tid>>2), c-range (tid&3)*64..+63.
  {
    const int wtok = tid >> 2;           // 0..63
    const int iw2 = wtok >> 3, s2 = wtok & 7;
    const int cg = (tid & 3) * 64;
    const float mu2 = smu[wtok], rs2 = srs[wtok];
    const int n2 = (bt >> 2) * 64 + (h >> 3) * 8 + iw2;
    const int l2 = (bt & 3) * 64 + (h & 7) * 8 + s2;
    short* xns = (short*)xn;
    const size_t addr = ((size_t)n2 * 256 + l2) * 256 + cg;
#pragma unroll
    for (int k = 0; k < 64; k += 4) {
      sh4 o;
#pragma unroll
      for (int e = 0; e < 4; ++e) {
        const int c = cg + k + e;
        const float v = bs2f(sX[c][wtok]);
        o[e] = f2bs((v - mu2) * rs2 * sGm[c] + sBt[c]);
      }
      *(sh4*)&xns[addr + k] = o;
    }
  }
}

// ---------------------------------------------------------------------------
// Kernel 2: MFMA qkv GEMM (R8-passing, unchanged; slab pitch 64, 5 blk/CU).
// ---------------------------------------------------------------------------
__global__ __launch_bounds__(256) void k_qkv(const bf16* __restrict__ A,
                                             const short* __restrict__ wb,
                                             bf16* __restrict__ out,
                                             int row_base) {
  __shared__ short smem[2 * 128 * 64];   // 32768 B
  short* sA = smem;
  short* sB = smem + 128 * 64;
  const int row0 = blockIdx.x * 128;
  const int col0 = blockIdx.y * 128;
  const int tid = threadIdx.x;
  const int wid = tid >> 6, lane = tid & 63;
  const int wy = wid >> 1, wx = wid & 1;
  const int l15 = lane & 15, quad = lane >> 4;
  const short* Ab = (const short*)A;

  const int lr = lane >> 3;
  const int swc = (lane & 7) ^ lr;

  f32x4 acc[4][4];
#pragma unroll
  for (int i = 0; i < 4; ++i)
#pragma unroll
    for (int j = 0; j < 4; ++j) acc[i][j] = (f32x4){0.f, 0.f, 0.f, 0.f};

  for (int k0 = 0; k0 < 256; k0 += 64) {
    if (k0) __syncthreads();
#pragma unroll
    for (int it = 0; it < 4; ++it) {
      const int rbase = wid * 32 + it * 8;
      gld16(sA + rbase * 64,
            Ab + (size_t)(row_base + row0 + rbase + lr) * 256 + k0 + swc * 8);
      gld16(sB + rbase * 64,
            wb + (size_t)(col0 + rbase + lr) * 256 + k0 + swc * 8);
    }
    asm volatile("s_waitcnt vmcnt(0)" ::: "memory");
    __syncthreads();
#pragma unroll
    for (int kk = 0; kk < 64; kk += 32) {
      const int ck = kk >> 3;
      short8 af[4], bfv[4];
#pragma unroll
      for (int i = 0; i < 4; ++i) {
        const int ar = wy * 64 + i * 16 + l15;
        af[i] = *(const short8*)(sA + ar * 64 + (((quad + ck) ^ (ar & 7)) * 8));
      }
#pragma unroll
      for (int j = 0; j < 4; ++j) {
        const int br = wx * 64 + j * 16 + l15;
        bfv[j] = *(const short8*)(sB + br * 64 + (((quad + ck) ^ (br & 7)) * 8));
      }
#pragma unroll
      for (int i = 0; i < 4; ++i)
#pragma unroll
        for (int j = 0; j < 4; ++j)
          acc[i][j] = __builtin_amdgcn_mfma_f32_16x16x32_bf16(af[i], bfv[j], acc[i][j], 0, 0, 0);
    }
  }

  __syncthreads();
  short* slab = smem + wid * (64 * 64);   // 64 rows x pitch 64, fits exactly
#pragma unroll
  for (int j = 0; j < 4; ++j) {
    const int col = col0 + wx * 64 + j * 16 + l15;
    const float bj = bs2f(wb[OB_QKV + col]);
#pragma unroll
    for (int i = 0; i < 4; ++i)
#pragma unroll
      for (int r = 0; r < 4; ++r)
        slab[(i * 16 + quad * 4 + r) * 64 + j * 16 + l15] = f2bs(acc[i][j][r] + bj);
  }
  {
    const int srow = lane >> 3;
    const int scol = (lane & 7) * 8;
    short* og = (short*)out;
#pragma unroll
    for (int it = 0; it < 8; ++it) {
      const int rloc = it * 8 + srow;
      short8 v = *(const short8*)&slab[rloc * 64 + scol];
      *(short8*)&og[(size_t)(row0 + wy * 64 + rloc) * 768 + col0 + wx * 64 + scol] = v;
    }
  }
}

// ---------------------------------------------------------------------------
// Kernel 3: MFMA attention — R9 REVERT: no lt unroll, plain launch bounds.
// (R9's unroll-2 + __launch_bounds__(256,4) forced VGPR to 64 -> sacc spills
// to scratch: FETCH 24.6->233 MB, WRITE 16->152 MB, dur 36->120 us. Both
// changes reverted; swapped QK^T + PV operand swap + direct O store kept.)
// ---------------------------------------------------------------------------
__global__ __launch_bounds__(256) void k_attn(const bf16* __restrict__ qkv,
                                              bf16* __restrict__ aout,
                                              int n_base, int nw_mask, int nw_shift) {
  const int n_loc = blockIdx.x & nw_mask, hh = blockIdx.x >> nw_shift;
  const int n_glob = n_base + n_loc;
  __shared__ short sK[256][32];      // 16 KB, linear, DMA-staged
  __shared__ short sVt[32][256];     // 16 KB, chunk-XOR key row&7
  __shared__ short sP[4][16][64];    // 8 KB, chunk-XOR key l15&7
  const int tid = threadIdx.x;
  const int wid = tid >> 6, lane = tid & 63;
  const int l15 = lane & 15, quad = lane >> 4;
  const int l7 = l15 & 7;
  const short* qg = (const short*)qkv;
  const size_t base = (size_t)n_loc * 256 * 768 + hh * 32;

  // K staging via global_load_lds: 4 instrs/wave, 16 rows x 32 shorts each.
#pragma unroll
  for (int it = 0; it < 4; ++it) {
    const int rbase = wid * 64 + it * 16;
    gld16(&sK[rbase][0],
          qg + base + (size_t)(rbase + (lane >> 2)) * 768 + 256 + (lane & 3) * 8);
  }
  // V transpose staging (manual scatter), physical chunk = (m>>3) ^ (d&7).
  for (int c = tid; c < 1024; c += 256) {
    const int m = c >> 2, d0 = (c & 3) * 8;
    short8 vv = *(const short8*)(qg + base + (size_t)m * 768 + 512 + d0);
#pragma unroll
    for (int j = 0; j < 8; ++j)
      sVt[d0 + j][(((m >> 3) ^ j) << 3) | (m & 7)] = vv[j];
  }
  asm volatile("s_waitcnt vmcnt(0)" ::: "memory");
  __syncthreads();

  const int R0 = wid * 64;
  const float esc = SCALE_F * LOG2E_F;

  for (int lt = 0; lt < 4; ++lt) {
    const int lrow = R0 + lt * 16;
    const short8 qf = *(const short8*)(qg + base + (size_t)(lrow + l15) * 768 + quad * 8);

    // QK^T swapped: sacc[t][r] = S[qrow=l15][kv = t*16 + quad*4 + r].
    f32x4 sacc[16];
    __builtin_amdgcn_s_setprio(1);
#pragma unroll
    for (int t = 0; t < 16; ++t) {
      sacc[t] = (f32x4){0.f, 0.f, 0.f, 0.f};
      const short8 kf = *(const short8*)&sK[t * 16 + l15][quad * 8];
      sacc[t] = __builtin_amdgcn_mfma_f32_16x16x32_bf16(kf, qf, sacc[t], 0, 0, 0);
    }
    __builtin_amdgcn_s_setprio(0);

    float sum = 0.f;
    f32x4 oacc[2] = {(f32x4){0.f, 0.f, 0.f, 0.f}, (f32x4){0.f, 0.f, 0.f, 0.f}};

#pragma unroll
    for (int ph = 0; ph < 4; ++ph) {
      // exp + pack + write: 4 t-tiles, one b64 (sh4) write each.
#pragma unroll
      for (int tp = 0; tp < 4; ++tp) {
        const int t = ph * 4 + tp;
        const float p0 = fexp2(sacc[t][0] * esc);
        const float p1 = fexp2(sacc[t][1] * esc);
        const float p2 = fexp2(sacc[t][2] * esc);
        const float p3 = fexp2(sacc[t][3] * esc);
        sum += (p0 + p1) + (p2 + p3);
        sh4 w;
        w[0] = f2bs(p0); w[1] = f2bs(p1); w[2] = f2bs(p2); w[3] = f2bs(p3);
        const int chunk = tp * 2 + (quad >> 1);           // local kv chunk 0..7
        *(sh4*)&sP[wid][l15][((chunk ^ l7) << 3) | ((quad & 1) * 4)] = w;
      }
      __builtin_amdgcn_s_setprio(1);
#pragma unroll
      for (int kk = 0; kk < 2; ++kk) {
        const int pphys = (kk * 4 + quad) ^ l7;           // phys chunk, row=l15
        const short8 pf = *(const short8*)&sP[wid][l15][pphys * 8];
#pragma unroll
        for (int dt = 0; dt < 2; ++dt) {
          const int vrow = dt * 16 + l15;
          const int cch = ph * 8 + kk * 4 + quad;         // global kv chunk
          const short8 vf = *(const short8*)&sVt[vrow][((cch ^ (vrow & 7)) * 8)];
          // A=Vt (rows=d), B=P (rows=q) -> O^T: row=d, col=q.
          oacc[dt] = __builtin_amdgcn_mfma_f32_16x16x32_bf16(vf, pf, oacc[dt], 0, 0, 0);
        }
      }
      __builtin_amdgcn_s_setprio(0);
    }

    // row-sum finish: reduce across quads (same l15 = same q-row = this
    // lane's output column). No redistribution needed.
    sum += __shfl_xor(sum, 16, 64);
    sum += __shfl_xor(sum, 32, 64);
    const float inv = frcp(sum);

    // Direct O store: lane (l15,quad) holds O[q=l15][d=dt*16+quad*4+r].
    {
      short* og = (short*)aout;
      const size_t obase =
          ((size_t)n_glob * 256 + lrow + l15) * 256 + hh * 32 + quad * 4;
#pragma unroll
      for (int dt = 0; dt < 2; ++dt) {
        sh4 w;
#pragma unroll
        for (int r = 0; r < 4; ++r) w[r] = f2bs(oacc[dt][r] * inv);
        *(sh4*)&og[obase + dt * 16] = w;
      }
    }
  }
}

// ---------------------------------------------------------------------------
// Kernel 4a: proj GEMM only -> tmp[token][c] (R8-passing, unchanged).
// ---------------------------------------------------------------------------
__global__ __launch_bounds__(256) void k_proj_g(const bf16* __restrict__ A,
                                                const short* __restrict__ wb,
                                                bf16* __restrict__ out) {
  __shared__ short smem[2 * 128 * 64];
  short* sA = smem;
  short* sB = smem + 128 * 64;
  const int row0 = blockIdx.x * 128;
  const int col0 = blockIdx.y * 128;
  const int tid = threadIdx.x;
  const int wid = tid >> 6, lane = tid & 63;
  const int wy = wid >> 1, wx = wid & 1;
  const int l15 = lane & 15, quad = lane >> 4;
  const short* Ab = (const short*)A;

  const int lr = lane >> 3;
  const int swc = (lane & 7) ^ lr;

  f32x4 acc[4][4];
#pragma unroll
  for (int i = 0; i < 4; ++i)
#pragma unroll
    for (int j = 0; j < 4; ++j) acc[i][j] = (f32x4){0.f, 0.f, 0.f, 0.f};

  for (int k0 = 0; k0 < 256; k0 += 64) {
    if (k0) __syncthreads();
#pragma unroll
    for (int it = 0; it < 4; ++it) {
      const int rbase = wid * 32 + it * 8;
      gld16(sA + rbase * 64,
            Ab + (size_t)(row0 + rbase + lr) * 256 + k0 + swc * 8);
      gld16(sB + rbase * 64,
            wb + OW_PROJ + (size_t)(col0 + rbase + lr) * 256 + k0 + swc * 8);
    }
    asm volatile("s_waitcnt vmcnt(0)" ::: "memory");
    __syncthreads();
#pragma unroll
    for (int kk = 0; kk < 64; kk += 32) {
      const int ck = kk >> 3;
      short8 af[4], bfv[4];
#pragma unroll
      for (int i = 0; i < 4; ++i) {
        const int ar = wy * 64 + i * 16 + l15;
        af[i] = *(const short8*)(sA + ar * 64 + (((quad + ck) ^ (ar & 7)) * 8));
      }
#pragma unroll
      for (int j = 0; j < 4; ++j) {
        const int br = wx * 64 + j * 16 + l15;
        bfv[j] = *(const short8*)(sB + br * 64 + (((quad + ck) ^ (br & 7)) * 8));
      }
#pragma unroll
      for (int i = 0; i < 4; ++i)
#pragma unroll
        for (int j = 0; j < 4; ++j)
          acc[i][j] = __builtin_amdgcn_mfma_f32_16x16x32_bf16(af[i], bfv[j], acc[i][j], 0, 0, 0);
    }
  }

  __syncthreads();
  short* slab = smem + wid * (64 * 64);   // pitch 64, fits exactly
#pragma unroll
  for (int j = 0; j < 4; ++j) {
    const int col = col0 + wx * 64 + j * 16 + l15;
    const float bj = bs2f(wb[OB_PROJ + col]);
#pragma unroll
    for (int i = 0; i < 4; ++i)
#pragma unroll
      for (int r = 0; r < 4; ++r)
        slab[(i * 16 + quad * 4 + r) * 64 + j * 16 + l15] = f2bs(acc[i][j][r] + bj);
  }
  {
    const int srow = lane >> 3;
    const int scol = (lane & 7) * 8;
    short* og = (short*)out;
#pragma unroll
    for (int it = 0; it < 8; ++it) {
      const int rloc = it * 8 + srow;
      short8 v = *(const short8*)&slab[rloc * 64 + scol];
      *(short8*)&og[(size_t)(row0 + wy * 64 + rloc) * 256 + col0 + wx * 64 + scol] = v;
    }
  }
}

// ---------------------------------------------------------------------------
// Kernel 4b: residual add + un-window, fully coalesced both sides (R8).
// ---------------------------------------------------------------------------
__global__ __launch_bounds__(256) void k_add(const bf16* __restrict__ tmp,
                                             const void* __restrict__ x,
                                             void* __restrict__ out) {
  const int tid = threadIdx.x;
  const int mode = probe_mode((const float*)x, tid);
  const int bt = blockIdx.x >> 6;      // 0..7
  const int h  = blockIdx.x & 63;      // 0..63

  __shared__ short sT2[256][68];       // [c][w], w-group swizzled

  const int n_b = (bt >> 2) * 64 + (h >> 3) * 8;
  const int l0  = (bt & 3) * 64 + (h & 7) * 8;
  const short* tg = (const short*)tmp;

#pragma unroll
  for (int i = 0; i < 8; ++i) {
    const int id = i * 256 + tid;
    const int w = id >> 5, c8 = (id & 31) * 8;
    const int row = (n_b + (w >> 3)) * 256 + l0 + (w & 7);
    const short8 v = *(const short8*)(tg + (size_t)row * 256 + c8);
    const int wg = ((w >> 2) ^ ((id & 31) & 15)) * 4 + (w & 3);
#pragma unroll
    for (int j = 0; j < 8; ++j) sT2[c8 + j][wg] = v[j];
  }
  __syncthreads();

  const int cl = tid >> 4;             // 0..15
  const int wi = tid & 15;             // 0..15
  const size_t gb = (size_t)bt * 1048576 + (size_t)h * 64 + wi * 4;
  for (int c0 = 0; c0 < 256; c0 += 16) {
    const int c = c0 + cl;
    const int k15 = (c >> 3) & 15;
    const sh4 pv = *(const sh4*)&sT2[c][((wi ^ k15) & 15) * 4];
    const size_t gaddr = gb + (size_t)c * 4096;
    const float4 xv = ldin4(x, gaddr, mode);
    float4 o;
    o.x = xv.x + bs2f(pv[0]);
    o.y = xv.y + bs2f(pv[1]);
    o.z = xv.z + bs2f(pv[2]);
    o.w = xv.w + bs2f(pv[3]);
    stout4(out, gaddr, mode, o);
  }
}

// ---------------------------------------------------------------------------
// Kernel 4 (fallback path only): MFMA proj GEMM + scatter epilogue.
// ---------------------------------------------------------------------------
__global__ __launch_bounds__(256) void k_proj(const bf16* __restrict__ A,
                                              const short* __restrict__ wb,
                                              const void* __restrict__ x,
                                              void* __restrict__ out) {
  const int tid = threadIdx.x;
  const int mode = probe_mode((const float*)x, tid);
  __shared__ short smem[2 * 128 * 64];
  __shared__ float sT[4][16][17];
  short* sA = smem;
  short* sB = smem + 128 * 64;
  const int row0 = blockIdx.x * 128;
  const int col0 = blockIdx.y * 128;
  const int wid = tid >> 6, lane = tid & 63;
  const int wy = wid >> 1, wx = wid & 1;
  const int l15 = lane & 15, quad = lane >> 4;
  const short* Ab = (const short*)A;

  const int lr = lane >> 3;
  const int swc = (lane & 7) ^ lr;

  f32x4 acc[4][4];
#pragma unroll
  for (int i = 0; i < 4; ++i)
#pragma unroll
    for (int j = 0; j < 4; ++j) acc[i][j] = (f32x4){0.f, 0.f, 0.f, 0.f};

  for (int k0 = 0; k0 < 256; k0 += 64) {
    if (k0) __syncthreads();
#pragma unroll
    for (int it = 0; it < 4; ++it) {
      const int rbase = wid * 32 + it * 8;
      gld16(sA + rbase * 64,
            Ab + (size_t)(row0 + rbase + lr) * 256 + k0 + swc * 8);
      gld16(sB + rbase * 64,
            wb + OW_PROJ + (size_t)(col0 + rbase + lr) * 256 + k0 + swc * 8);
    }
    asm volatile("s_waitcnt vmcnt(0)" ::: "memory");
    __syncthreads();
#pragma unroll
    for (int kk = 0; kk < 64; kk += 32) {
      const int ck = kk >> 3;
      short8 af[4], bfv[4];
#pragma unroll
      for (int i = 0; i < 4; ++i) {
        const int ar = wy * 64 + i * 16 + l15;
        af[i] = *(const short8*)(sA + ar * 64 + (((quad + ck) ^ (ar & 7)) * 8));
      }
#pragma unroll
      for (int j = 0; j < 4; ++j) {
        const int br = wx * 64 + j * 16 + l15;
        bfv[j] = *(const short8*)(sB + br * 64 + (((quad + ck) ^ (br & 7)) * 8));
      }
#pragma unroll
      for (int i = 0; i < 4; ++i)
#pragma unroll
        for (int j = 0; j < 4; ++j)
          acc[i][j] = __builtin_amdgcn_mfma_f32_16x16x32_bf16(af[i], bfv[j], acc[i][j], 0, 0, 0);
    }
  }

#pragma unroll
  for (int i = 0; i < 4; ++i) {
#pragma unroll
    for (int j = 0; j < 4; ++j) {
#pragma unroll
      for (int r = 0; r < 4; ++r)
        sT[wid][quad * 4 + r][l15] = acc[i][j][r];
      asm volatile("s_waitcnt lgkmcnt(0)" ::: "memory");
#pragma unroll
      for (int r2 = 0; r2 < 4; ++r2) {
        const float v = sT[wid][l15][quad * 4 + r2];
        const int row = row0 + wy * 64 + i * 16 + l15;
        const int c   = col0 + wx * 64 + j * 16 + quad * 4 + r2;
        const int n = row >> 8, l = row & 255;
        const int b = n >> 6, ih = (n >> 3) & 7, iw = n & 7;
        const int tt = l >> 6, rr = (l >> 3) & 7, ss = l & 7;
        const int btl = b * 4 + tt;
        const size_t gaddr = (size_t)btl * 1048576 + (size_t)c * 4096 +
                             (ih * 8 + rr) * 64 + iw * 8 + ss;
        const float o = v + bs2f(wb[OB_PROJ + c]) + ldin(x, gaddr, mode);
        stout(out, gaddr, mode, o);
      }
      asm volatile("s_waitcnt lgkmcnt(0)" ::: "memory");
    }
  }
}

// ---------------------------------------------------------------------------
extern "C" void kernel_launch(void* const* d_in, const int* in_sizes, int n_in,
                              void* d_out, int out_size, void* d_ws, size_t ws_size,
                              hipStream_t stream) {
  (void)in_sizes; (void)n_in; (void)out_size;
  const void* x      = d_in[0];
  const void* w_qkv  = d_in[1];
  const void* b_qkv  = d_in[2];
  const void* w_proj = d_in[3];
  const void* b_proj = d_in[4];
  const void* gamma  = d_in[5];
  const void* beta   = d_in[6];

  char* ws = (char*)d_ws;
  short* wbuf  = (short*)(ws + 1024);                       // NWB*2 = 526336 B
  bf16* xnbuf  = (bf16*)(ws + 1024 + 526336);               // 16 MiB
  bf16* qkvb   = (bf16*)(ws + 1024 + 526336 + 16777216);    // full 48 MiB / chunk 12.6 MiB

  const size_t need_full = 1024 + 526336 + 16777216 + (size_t)32768 * 768 * 2;

  hipLaunchKernelGGL(k_ln, dim3(512), dim3(256), 0, stream, x, gamma, beta, xnbuf,
                     w_qkv, w_proj, b_qkv, b_proj, wbuf);

  if (ws_size >= need_full) {
    hipLaunchKernelGGL(k_qkv, dim3(256, 6), dim3(256), 0, stream,
                       xnbuf, wbuf, qkvb, 0);
    hipLaunchKernelGGL(k_attn, dim3(1024), dim3(256), 0, stream,
                       qkvb, xnbuf, 0, 127, 7);
    bf16* tmpb = qkvb;
    hipLaunchKernelGGL(k_proj_g, dim3(256, 2), dim3(256), 0, stream,
                       xnbuf, wbuf, tmpb);
    hipLaunchKernelGGL(k_add, dim3(512), dim3(256), 0, stream,
                       tmpb, x, d_out);
  } else {
    for (int c = 0; c < 4; ++c) {
      hipLaunchKernelGGL(k_qkv, dim3(64, 6), dim3(256), 0, stream,
                         xnbuf, wbuf, qkvb, c * ROWS_CHUNK);
      hipLaunchKernelGGL(k_attn, dim3(NW_CHUNK * 8), dim3(256), 0, stream,
                         qkvb, xnbuf, c * NW_CHUNK, NW_CHUNK - 1, 5);
    }
    hipLaunchKernelGGL(k_proj, dim3(256, 2), dim3(256), 0, stream,
                       xnbuf, wbuf, x, d_out);
  }
}

// Round 11
// 164.848 us; speedup vs baseline: 1.5650x; 1.0297x over previous
//
#include <hip/hip_runtime.h>
#include <hip/hip_bf16.h>

typedef __hip_bfloat16 bf16;
typedef __attribute__((ext_vector_type(8))) short short8;   // 8 bf16 bits (4 VGPRs)
typedef __attribute__((ext_vector_type(4))) short sh4;      // 4 bf16 bits (8 B)
typedef __attribute__((ext_vector_type(4))) float f32x4;    // MFMA C/D

// Problem constants: B=2, T=4, H=W=64, C=256, ws=8
// N = 128 windows, L = 256 tokens, C = 256, heads = 8, head_dim = 32
#define SCALE_F 0.17677669529663687f
#define LOG2E_F 1.4426950408889634f
#define EPS_F 1e-5f
#define NW_CHUNK 32                 // windows per chunk (fallback path)
#define ROWS_CHUNK (NW_CHUNK * 256)

// converted bf16 weight buffer layout (offsets in shorts)
#define OW_QKV  0
#define OW_PROJ 196608
#define OB_QKV  262144
#define OB_PROJ 262912
#define NWB     263168

__device__ __forceinline__ float b2f(bf16 v) { return __bfloat162float(v); }
__device__ __forceinline__ bf16 f2b(float v) { return __float2bfloat16(v); }
__device__ __forceinline__ short f2bs(float v) { bf16 h = f2b(v); return *(short*)&h; }
__device__ __forceinline__ float bs2f(short s) { bf16 h = *(bf16*)&s; return __bfloat162float(h); }

#if __has_builtin(__builtin_amdgcn_exp2f)
__device__ __forceinline__ float fexp2(float x) { return __builtin_amdgcn_exp2f(x); }
#else
__device__ __forceinline__ float fexp2(float x) { return exp2f(x); }
#endif
#if __has_builtin(__builtin_amdgcn_rcpf)
__device__ __forceinline__ float frcp(float x) { return __builtin_amdgcn_rcpf(x); }
#else
__device__ __forceinline__ float frcp(float x) { return 1.0f / x; }
#endif

__device__ __forceinline__ float ldin(const void* p, size_t i, int mode) {
  if (mode) return ((const float*)p)[i];
  return b2f(((const bf16*)p)[i]);
}
__device__ __forceinline__ void stout(void* p, size_t i, int mode, float v) {
  if (mode) ((float*)p)[i] = v;
  else      ((bf16*)p)[i] = f2b(v);
}
__device__ __forceinline__ float4 ldin4(const void* p, size_t i, int mode) {
  if (mode) return *(const float4*)((const float*)p + i);
  const sh4 s = *(const sh4*)((const short*)p + i);
  return make_float4(bs2f(s[0]), bs2f(s[1]), bs2f(s[2]), bs2f(s[3]));
}
__device__ __forceinline__ void stout4(void* p, size_t i, int mode, float4 v) {
  if (mode) { *(float4*)((float*)p + i) = v; }
  else {
    sh4 s; s[0] = f2bs(v.x); s[1] = f2bs(v.y); s[2] = f2bs(v.z); s[3] = f2bs(v.w);
    *(sh4*)((short*)p + i) = s;
  }
}

// Inline dtype probe: every block computes mode locally from x[0..1023].
__device__ __forceinline__ int probe_mode(const float* xf, int tid) {
  __shared__ int s_cnt;
  if (tid == 0) s_cnt = 0;
  __syncthreads();
  int bad = 0;
#pragma unroll
  for (int i = 0; i < 4; ++i) {
    const float v = xf[tid * 4 + i];
    if (!(fabsf(v) < 1e20f)) bad++;
  }
  if (bad) atomicAdd(&s_cnt, bad);
  __syncthreads();
  return (s_cnt < 8) ? 1 : 0;
}

// async global->LDS DMA, 16 B/lane; LDS dst wave-uniform, HW writes lane l's
// 16 B at dst + l*16. Global src is per-lane.
__device__ __forceinline__ void gld16(void* lds, const void* g) {
  __builtin_amdgcn_global_load_lds(
      (const __attribute__((address_space(1))) unsigned int*)g,
      (__attribute__((address_space(3))) unsigned int*)lds, 16, 0, 0);
}

// ---------------------------------------------------------------------------
// Kernel 1: gather + LayerNorm + merged weight cast (R10-passing, unchanged).
// ---------------------------------------------------------------------------
__global__ __launch_bounds__(256) void k_ln(const void* __restrict__ x,
                                            const void* __restrict__ gamma,
                                            const void* __restrict__ beta,
                                            bf16* __restrict__ xn,
                                            const void* __restrict__ w1,
                                            const void* __restrict__ w2,
                                            const void* __restrict__ b1,
                                            const void* __restrict__ b2,
                                            short* __restrict__ wbuf) {
  const int tid = threadIdx.x;
  const int mode = probe_mode((const float*)x, tid);

  {
    const int base = (blockIdx.x * 256 + tid) * 2;
#pragma unroll
    for (int e = 0; e < 2; ++e) {
      const int i = base + e;
      float v;
      if (i < OW_PROJ)      v = ldin(w1, i, mode);
      else if (i < OB_QKV)  v = ldin(w2, i - OW_PROJ, mode);
      else if (i < OB_PROJ) v = ldin(b1, i - OB_QKV, mode);
      else                  v = ldin(b2, i - OB_PROJ, mode);
      wbuf[i] = f2bs(v);
    }
    if (blockIdx.x == 0) {  // tail: 262144..NWB-1 (1024 elems)
#pragma unroll
      for (int e = 0; e < 4; ++e) {
        const int i = 262144 + tid * 4 + e;
        float v;
        if (i < OB_PROJ) v = ldin(b1, i - OB_QKV, mode);
        else             v = ldin(b2, i - OB_PROJ, mode);
        wbuf[i] = f2bs(v);
      }
    }
  }

  const int bt = blockIdx.x >> 6;      // 0..7
  const int h  = blockIdx.x & 63;      // 0..63
  const int cl = tid >> 4;             // 0..15
  const int wi = tid & 15;             // 0..15

  __shared__ short sX[256][68];
  __shared__ float sred[16][65];
  __shared__ float sqred[16][65];
  __shared__ float smu[64], srs[64];
  __shared__ float sGm[256], sBt[256];

  sGm[tid] = ldin(gamma, tid, mode);
  sBt[tid] = ldin(beta, tid, mode);

  const size_t gbase = (size_t)bt * 1048576 + (size_t)h * 64 + wi * 4;
  float s4[4] = {0.f, 0.f, 0.f, 0.f}, q4[4] = {0.f, 0.f, 0.f, 0.f};
  for (int c0 = 0; c0 < 256; c0 += 16) {
    const int c = c0 + cl;
    const float4 v = ldin4(x, gbase + (size_t)c * 4096, mode);
    s4[0] += v.x; q4[0] += v.x * v.x;
    s4[1] += v.y; q4[1] += v.y * v.y;
    s4[2] += v.z; q4[2] += v.z * v.z;
    s4[3] += v.w; q4[3] += v.w * v.w;
    sh4 b;
    b[0] = f2bs(v.x); b[1] = f2bs(v.y); b[2] = f2bs(v.z); b[3] = f2bs(v.w);
    *(sh4*)&sX[c][wi * 4] = b;
  }
#pragma unroll
  for (int k = 0; k < 4; ++k) {
    sred[cl][wi * 4 + k] = s4[k];
    sqred[cl][wi * 4 + k] = q4[k];
  }
  __syncthreads();
  if (tid < 64) {
    float a = 0.f, q = 0.f;
#pragma unroll
    for (int g = 0; g < 16; ++g) { a += sred[g][tid]; q += sqred[g][tid]; }
    const float mu = a * (1.0f / 256.0f);
    const float var = fmaxf(q * (1.0f / 256.0f) - mu * mu, 0.0f);
    smu[tid] = mu; srs[tid] = rsqrtf(var + EPS_F);
  }
  __syncthreads();

  // Phase 2: thread -> one token (w = tid>>2), c-range (tid&3)*64..+63.
  {
    const int wtok = tid >> 2;           // 0..63
    const int iw2 = wtok >> 3, s2 = wtok & 7;
    const int cg = (tid & 3) * 64;
    const float mu2 = smu[wtok], rs2 = srs[wtok];
    const int n2 = (bt >> 2) * 64 + (h >> 3) * 8 + iw2;
    const int l2 = (bt & 3) * 64 + (h & 7) * 8 + s2;
    short* xns = (short*)xn;
    const size_t addr = ((size_t)n2 * 256 + l2) * 256 + cg;
#pragma unroll
    for (int k = 0; k < 64; k += 4) {
      sh4 o;
#pragma unroll
      for (int e = 0; e < 4; ++e) {
        const int c = cg + k + e;
        const float v = bs2f(sX[c][wtok]);
        o[e] = f2bs((v - mu2) * rs2 * sGm[c] + sBt[c]);
      }
      *(sh4*)&xns[addr + k] = o;
    }
  }
}

// ---------------------------------------------------------------------------
// Kernel 2: MFMA qkv GEMM (R10-passing, unchanged; slab pitch 64, 5 blk/CU).
// ---------------------------------------------------------------------------
__global__ __launch_bounds__(256) void k_qkv(const bf16* __restrict__ A,
                                             const short* __restrict__ wb,
                                             bf16* __restrict__ out,
                                             int row_base) {
  __shared__ short smem[2 * 128 * 64];   // 32768 B
  short* sA = smem;
  short* sB = smem + 128 * 64;
  const int row0 = blockIdx.x * 128;
  const int col0 = blockIdx.y * 128;
  const int tid = threadIdx.x;
  const int wid = tid >> 6, lane = tid & 63;
  const int wy = wid >> 1, wx = wid & 1;
  const int l15 = lane & 15, quad = lane >> 4;
  const short* Ab = (const short*)A;

  const int lr = lane >> 3;
  const int swc = (lane & 7) ^ lr;

  f32x4 acc[4][4];
#pragma unroll
  for (int i = 0; i < 4; ++i)
#pragma unroll
    for (int j = 0; j < 4; ++j) acc[i][j] = (f32x4){0.f, 0.f, 0.f, 0.f};

  for (int k0 = 0; k0 < 256; k0 += 64) {
    if (k0) __syncthreads();
#pragma unroll
    for (int it = 0; it < 4; ++it) {
      const int rbase = wid * 32 + it * 8;
      gld16(sA + rbase * 64,
            Ab + (size_t)(row_base + row0 + rbase + lr) * 256 + k0 + swc * 8);
      gld16(sB + rbase * 64,
            wb + (size_t)(col0 + rbase + lr) * 256 + k0 + swc * 8);
    }
    asm volatile("s_waitcnt vmcnt(0)" ::: "memory");
    __syncthreads();
#pragma unroll
    for (int kk = 0; kk < 64; kk += 32) {
      const int ck = kk >> 3;
      short8 af[4], bfv[4];
#pragma unroll
      for (int i = 0; i < 4; ++i) {
        const int ar = wy * 64 + i * 16 + l15;
        af[i] = *(const short8*)(sA + ar * 64 + (((quad + ck) ^ (ar & 7)) * 8));
      }
#pragma unroll
      for (int j = 0; j < 4; ++j) {
        const int br = wx * 64 + j * 16 + l15;
        bfv[j] = *(const short8*)(sB + br * 64 + (((quad + ck) ^ (br & 7)) * 8));
      }
#pragma unroll
      for (int i = 0; i < 4; ++i)
#pragma unroll
        for (int j = 0; j < 4; ++j)
          acc[i][j] = __builtin_amdgcn_mfma_f32_16x16x32_bf16(af[i], bfv[j], acc[i][j], 0, 0, 0);
    }
  }

  __syncthreads();
  short* slab = smem + wid * (64 * 64);   // 64 rows x pitch 64, fits exactly
#pragma unroll
  for (int j = 0; j < 4; ++j) {
    const int col = col0 + wx * 64 + j * 16 + l15;
    const float bj = bs2f(wb[OB_QKV + col]);
#pragma unroll
    for (int i = 0; i < 4; ++i)
#pragma unroll
      for (int r = 0; r < 4; ++r)
        slab[(i * 16 + quad * 4 + r) * 64 + j * 16 + l15] = f2bs(acc[i][j][r] + bj);
  }
  {
    const int srow = lane >> 3;
    const int scol = (lane & 7) * 8;
    short* og = (short*)out;
#pragma unroll
    for (int it = 0; it < 8; ++it) {
      const int rloc = it * 8 + srow;
      short8 v = *(const short8*)&slab[rloc * 64 + scol];
      *(short8*)&og[(size_t)(row0 + wy * 64 + rloc) * 768 + col0 + wx * 64 + scol] = v;
    }
  }
}

// ---------------------------------------------------------------------------
// Kernel 3: MFMA attention (R10-passing, unchanged: swapped QK^T, PV operand
// swap, direct O store, no lt unroll, plain launch bounds).
// ---------------------------------------------------------------------------
__global__ __launch_bounds__(256) void k_attn(const bf16* __restrict__ qkv,
                                              bf16* __restrict__ aout,
                                              int n_base, int nw_mask, int nw_shift) {
  const int n_loc = blockIdx.x & nw_mask, hh = blockIdx.x >> nw_shift;
  const int n_glob = n_base + n_loc;
  __shared__ short sK[256][32];      // 16 KB, linear, DMA-staged
  __shared__ short sVt[32][256];     // 16 KB, chunk-XOR key row&7
  __shared__ short sP[4][16][64];    // 8 KB, chunk-XOR key l15&7
  const int tid = threadIdx.x;
  const int wid = tid >> 6, lane = tid & 63;
  const int l15 = lane & 15, quad = lane >> 4;
  const int l7 = l15 & 7;
  const short* qg = (const short*)qkv;
  const size_t base = (size_t)n_loc * 256 * 768 + hh * 32;

  // K staging via global_load_lds: 4 instrs/wave, 16 rows x 32 shorts each.
#pragma unroll
  for (int it = 0; it < 4; ++it) {
    const int rbase = wid * 64 + it * 16;
    gld16(&sK[rbase][0],
          qg + base + (size_t)(rbase + (lane >> 2)) * 768 + 256 + (lane & 3) * 8);
  }
  // V transpose staging (manual scatter), physical chunk = (m>>3) ^ (d&7).
  for (int c = tid; c < 1024; c += 256) {
    const int m = c >> 2, d0 = (c & 3) * 8;
    short8 vv = *(const short8*)(qg + base + (size_t)m * 768 + 512 + d0);
#pragma unroll
    for (int j = 0; j < 8; ++j)
      sVt[d0 + j][(((m >> 3) ^ j) << 3) | (m & 7)] = vv[j];
  }
  asm volatile("s_waitcnt vmcnt(0)" ::: "memory");
  __syncthreads();

  const int R0 = wid * 64;
  const float esc = SCALE_F * LOG2E_F;

  for (int lt = 0; lt < 4; ++lt) {
    const int lrow = R0 + lt * 16;
    const short8 qf = *(const short8*)(qg + base + (size_t)(lrow + l15) * 768 + quad * 8);

    // QK^T swapped: sacc[t][r] = S[qrow=l15][kv = t*16 + quad*4 + r].
    f32x4 sacc[16];
    __builtin_amdgcn_s_setprio(1);
#pragma unroll
    for (int t = 0; t < 16; ++t) {
      sacc[t] = (f32x4){0.f, 0.f, 0.f, 0.f};
      const short8 kf = *(const short8*)&sK[t * 16 + l15][quad * 8];
      sacc[t] = __builtin_amdgcn_mfma_f32_16x16x32_bf16(kf, qf, sacc[t], 0, 0, 0);
    }
    __builtin_amdgcn_s_setprio(0);

    float sum = 0.f;
    f32x4 oacc[2] = {(f32x4){0.f, 0.f, 0.f, 0.f}, (f32x4){0.f, 0.f, 0.f, 0.f}};

#pragma unroll
    for (int ph = 0; ph < 4; ++ph) {
      // exp + pack + write: 4 t-tiles, one b64 (sh4) write each.
#pragma unroll
      for (int tp = 0; tp < 4; ++tp) {
        const int t = ph * 4 + tp;
        const float p0 = fexp2(sacc[t][0] * esc);
        const float p1 = fexp2(sacc[t][1] * esc);
        const float p2 = fexp2(sacc[t][2] * esc);
        const float p3 = fexp2(sacc[t][3] * esc);
        sum += (p0 + p1) + (p2 + p3);
        sh4 w;
        w[0] = f2bs(p0); w[1] = f2bs(p1); w[2] = f2bs(p2); w[3] = f2bs(p3);
        const int chunk = tp * 2 + (quad >> 1);           // local kv chunk 0..7
        *(sh4*)&sP[wid][l15][((chunk ^ l7) << 3) | ((quad & 1) * 4)] = w;
      }
      __builtin_amdgcn_s_setprio(1);
#pragma unroll
      for (int kk = 0; kk < 2; ++kk) {
        const int pphys = (kk * 4 + quad) ^ l7;           // phys chunk, row=l15
        const short8 pf = *(const short8*)&sP[wid][l15][pphys * 8];
#pragma unroll
        for (int dt = 0; dt < 2; ++dt) {
          const int vrow = dt * 16 + l15;
          const int cch = ph * 8 + kk * 4 + quad;         // global kv chunk
          const short8 vf = *(const short8*)&sVt[vrow][((cch ^ (vrow & 7)) * 8)];
          // A=Vt (rows=d), B=P (rows=q) -> O^T: row=d, col=q.
          oacc[dt] = __builtin_amdgcn_mfma_f32_16x16x32_bf16(vf, pf, oacc[dt], 0, 0, 0);
        }
      }
      __builtin_amdgcn_s_setprio(0);
    }

    // row-sum finish: reduce across quads (same l15 = same q-row = this
    // lane's output column). No redistribution needed.
    sum += __shfl_xor(sum, 16, 64);
    sum += __shfl_xor(sum, 32, 64);
    const float inv = frcp(sum);

    // Direct O store: lane (l15,quad) holds O[q=l15][d=dt*16+quad*4+r].
    {
      short* og = (short*)aout;
      const size_t obase =
          ((size_t)n_glob * 256 + lrow + l15) * 256 + hh * 32 + quad * 4;
#pragma unroll
      for (int dt = 0; dt < 2; ++dt) {
        sh4 w;
#pragma unroll
        for (int r = 0; r < 4; ++r) w[r] = f2bs(oacc[dt][r] * inv);
        *(sh4*)&og[obase + dt * 16] = w;
      }
    }
  }
}

// ---------------------------------------------------------------------------
// Kernel 4: FUSED proj GEMM + residual add + un-window. Replaces the
// proj_g -> tmp -> add pipeline (saves 33.6 MB tmp round trip + a kernel
// boundary). Block = (bt, h) like k_add: its 64 tokens (w = iw*8+s) are
// 8x 4KB contiguous chunks of aout, owned by exactly one block.
//   GEMM: out64[tok][c] = A[64][256] @ W^T + bias; BK=64, 4 K-steps,
//   gld16 staging + chunk-XOR swizzle copied from k_qkv (row bases all
//   =0 mod 8, so the row&7 keys are unchanged). Wave w owns tokens
//   w*16..+15 x all 256 c (16 col-tiles, acc[16]).
//   Epilogue: bias-added bf16 -> sT2[256][68] (repurposed staging LDS;
//   col = ((w>>2)^((c>>3)&15)&15)*4 + (w&3), matching k_add's phase-2
//   read exactly), then k_add's coalesced float4 x-read/out-write.
// Numerics identical: same bf16 rounding point where tmp used to round.
// LDS 40960 B => 4 blocks/CU; grid 512 => all-resident, no tail.
// ---------------------------------------------------------------------------
__global__ __launch_bounds__(256) void k_projadd(const bf16* __restrict__ A,
                                                 const short* __restrict__ wb,
                                                 const void* __restrict__ x,
                                                 void* __restrict__ out) {
  const int tid = threadIdx.x;
  const int mode = probe_mode((const float*)x, tid);
  __shared__ short smem[64 * 64 + 256 * 64];   // 20480 shorts = 40960 B
  short* sA = smem;                  // [64][64], chunk-swizzled
  short* sB = smem + 64 * 64;        // [256][64], chunk-swizzled
  const int bt = blockIdx.x >> 6;    // 0..7
  const int h  = blockIdx.x & 63;    // 0..63
  const int wid = tid >> 6, lane = tid & 63;
  const int l15 = lane & 15, quad = lane >> 4;
  const short* Ab = (const short*)A;

  const int n_b = (bt >> 2) * 64 + (h >> 3) * 8;
  const int l0  = (bt & 3) * 64 + (h & 7) * 8;

  const int lr = lane >> 3;              // 0..7 sub-row within 8-row DMA slab
  const int swc = (lane & 7) ^ lr;       // pre-swizzled source chunk

  f32x4 acc[16];
#pragma unroll
  for (int j = 0; j < 16; ++j) acc[j] = (f32x4){0.f, 0.f, 0.f, 0.f};

  for (int k0 = 0; k0 < 256; k0 += 64) {
    if (k0) __syncthreads();
    // stage A: 64 token rows; wave stages rows wid*16 + it*8 (+lr).
    // token t = rt+lr: aout row = (n_b + (t>>3))*256 + l0 + (t&7); rt%8==0
    // so t>>3 = rt>>3, t&7 = lr.
#pragma unroll
    for (int it = 0; it < 2; ++it) {
      const int rt = wid * 16 + it * 8;
      const int grow = (n_b + (rt >> 3)) * 256 + l0 + lr;
      gld16(sA + rt * 64, Ab + (size_t)grow * 256 + k0 + swc * 8);
    }
    // stage B (W rows = output c): 256 rows; wave stages wid*64 + it*8.
#pragma unroll
    for (int it = 0; it < 8; ++it) {
      const int rb = wid * 64 + it * 8;
      gld16(sB + rb * 64,
            wb + OW_PROJ + (size_t)(rb + lr) * 256 + k0 + swc * 8);
    }
    asm volatile("s_waitcnt vmcnt(0)" ::: "memory");
    __syncthreads();
#pragma unroll
    for (int kk = 0; kk < 64; kk += 32) {
      const int ck = kk >> 3;
      const int ar = wid * 16 + l15;      // wave's token row (ar&7 == l15&7)
      const short8 af = *(const short8*)(sA + ar * 64 + (((quad + ck) ^ (ar & 7)) * 8));
#pragma unroll
      for (int j = 0; j < 16; ++j) {
        const int br = j * 16 + l15;
        const short8 bfv = *(const short8*)(sB + br * 64 + (((quad + ck) ^ (br & 7)) * 8));
        acc[j] = __builtin_amdgcn_mfma_f32_16x16x32_bf16(af, bfv, acc[j], 0, 0, 0);
      }
    }
  }

  // Epilogue 1: bias + bf16 round -> sT2[c][w-slot] (k_add's layout).
  // Lane holds D[tok = wid*16 + quad*4 + r][c = j*16 + l15];
  // w = tok, w>>2 = wid*4+quad, w&3 = r -> one sh4 write per j.
  __syncthreads();                       // all waves done with sA/sB
  short* sT2 = smem;                     // [256][68] = 17408 shorts, fits
  {
    const int wq = wid * 4 + quad;       // w>>2
#pragma unroll
    for (int j = 0; j < 16; ++j) {
      const int c = j * 16 + l15;
      const float bj = bs2f(wb[OB_PROJ + c]);
      const int col = ((wq ^ ((c >> 3) & 15)) & 15) * 4;
      sh4 o;
#pragma unroll
      for (int r = 0; r < 4; ++r) o[r] = f2bs(acc[j][r] + bj);
      *(sh4*)&sT2[c * 68 + col] = o;
    }
  }
  __syncthreads();                       // cross-wave: phase 2 reads all

  // Epilogue 2 (k_add phase-2 verbatim): coalesced float4 over (c, w-quad).
  {
    const int cl = tid >> 4;             // 0..15
    const int wi = tid & 15;             // 0..15
    const size_t gb = (size_t)bt * 1048576 + (size_t)h * 64 + wi * 4;
    for (int c0 = 0; c0 < 256; c0 += 16) {
      const int c = c0 + cl;
      const int k15 = (c >> 3) & 15;
      const sh4 pv = *(const sh4*)&sT2[c * 68 + ((wi ^ k15) & 15) * 4];
      const size_t gaddr = gb + (size_t)c * 4096;
      const float4 xv = ldin4(x, gaddr, mode);
      float4 o;
      o.x = xv.x + bs2f(pv[0]);
      o.y = xv.y + bs2f(pv[1]);
      o.z = xv.z + bs2f(pv[2]);
      o.w = xv.w + bs2f(pv[3]);
      stout4(out, gaddr, mode, o);
    }
  }
}

// ---------------------------------------------------------------------------
// Kernel 4 (fallback path only): MFMA proj GEMM + scatter epilogue.
// ---------------------------------------------------------------------------
__global__ __launch_bounds__(256) void k_proj(const bf16* __restrict__ A,
                                              const short* __restrict__ wb,
                                              const void* __restrict__ x,
                                              void* __restrict__ out) {
  const int tid = threadIdx.x;
  const int mode = probe_mode((const float*)x, tid);
  __shared__ short smem[2 * 128 * 64];
  __shared__ float sT[4][16][17];
  short* sA = smem;
  short* sB = smem + 128 * 64;
  const int row0 = blockIdx.x * 128;
  const int col0 = blockIdx.y * 128;
  const int wid = tid >> 6, lane = tid & 63;
  const int wy = wid >> 1, wx = wid & 1;
  const int l15 = lane & 15, quad = lane >> 4;
  const short* Ab = (const short*)A;

  const int lr = lane >> 3;
  const int swc = (lane & 7) ^ lr;

  f32x4 acc[4][4];
#pragma unroll
  for (int i = 0; i < 4; ++i)
#pragma unroll
    for (int j = 0; j < 4; ++j) acc[i][j] = (f32x4){0.f, 0.f, 0.f, 0.f};

  for (int k0 = 0; k0 < 256; k0 += 64) {
    if (k0) __syncthreads();
#pragma unroll
    for (int it = 0; it < 4; ++it) {
      const int rbase = wid * 32 + it * 8;
      gld16(sA + rbase * 64,
            Ab + (size_t)(row0 + rbase + lr) * 256 + k0 + swc * 8);
      gld16(sB + rbase * 64,
            wb + OW_PROJ + (size_t)(col0 + rbase + lr) * 256 + k0 + swc * 8);
    }
    asm volatile("s_waitcnt vmcnt(0)" ::: "memory");
    __syncthreads();
#pragma unroll
    for (int kk = 0; kk < 64; kk += 32) {
      const int ck = kk >> 3;
      short8 af[4], bfv[4];
#pragma unroll
      for (int i = 0; i < 4; ++i) {
        const int ar = wy * 64 + i * 16 + l15;
        af[i] = *(const short8*)(sA + ar * 64 + (((quad + ck) ^ (ar & 7)) * 8));
      }
#pragma unroll
      for (int j = 0; j < 4; ++j) {
        const int br = wx * 64 + j * 16 + l15;
        bfv[j] = *(const short8*)(sB + br * 64 + (((quad + ck) ^ (br & 7)) * 8));
      }
#pragma unroll
      for (int i = 0; i < 4; ++i)
#pragma unroll
        for (int j = 0; j < 4; ++j)
          acc[i][j] = __builtin_amdgcn_mfma_f32_16x16x32_bf16(af[i], bfv[j], acc[i][j], 0, 0, 0);
    }
  }

#pragma unroll
  for (int i = 0; i < 4; ++i) {
#pragma unroll
    for (int j = 0; j < 4; ++j) {
#pragma unroll
      for (int r = 0; r < 4; ++r)
        sT[wid][quad * 4 + r][l15] = acc[i][j][r];
      asm volatile("s_waitcnt lgkmcnt(0)" ::: "memory");
#pragma unroll
      for (int r2 = 0; r2 < 4; ++r2) {
        const float v = sT[wid][l15][quad * 4 + r2];
        const int row = row0 + wy * 64 + i * 16 + l15;
        const int c   = col0 + wx * 64 + j * 16 + quad * 4 + r2;
        const int n = row >> 8, l = row & 255;
        const int b = n >> 6, ih = (n >> 3) & 7, iw = n & 7;
        const int tt = l >> 6, rr = (l >> 3) & 7, ss = l & 7;
        const int btl = b * 4 + tt;
        const size_t gaddr = (size_t)btl * 1048576 + (size_t)c * 4096 +
                             (ih * 8 + rr) * 64 + iw * 8 + ss;
        const float o = v + bs2f(wb[OB_PROJ + c]) + ldin(x, gaddr, mode);
        stout(out, gaddr, mode, o);
      }
      asm volatile("s_waitcnt lgkmcnt(0)" ::: "memory");
    }
  }
}

// ---------------------------------------------------------------------------
extern "C" void kernel_launch(void* const* d_in, const int* in_sizes, int n_in,
                              void* d_out, int out_size, void* d_ws, size_t ws_size,
                              hipStream_t stream) {
  (void)in_sizes; (void)n_in; (void)out_size;
  const void* x      = d_in[0];
  const void* w_qkv  = d_in[1];
  const void* b_qkv  = d_in[2];
  const void* w_proj = d_in[3];
  const void* b_proj = d_in[4];
  const void* gamma  = d_in[5];
  const void* beta   = d_in[6];

  char* ws = (char*)d_ws;
  short* wbuf  = (short*)(ws + 1024);                       // NWB*2 = 526336 B
  bf16* xnbuf  = (bf16*)(ws + 1024 + 526336);               // 16 MiB
  bf16* qkvb   = (bf16*)(ws + 1024 + 526336 + 16777216);    // full 48 MiB / chunk 12.6 MiB

  const size_t need_full = 1024 + 526336 + 16777216 + (size_t)32768 * 768 * 2;

  hipLaunchKernelGGL(k_ln, dim3(512), dim3(256), 0, stream, x, gamma, beta, xnbuf,
                     w_qkv, w_proj, b_qkv, b_proj, wbuf);

  if (ws_size >= need_full) {
    hipLaunchKernelGGL(k_qkv, dim3(256, 6), dim3(256), 0, stream,
                       xnbuf, wbuf, qkvb, 0);
    hipLaunchKernelGGL(k_attn, dim3(1024), dim3(256), 0, stream,
                       qkvb, xnbuf, 0, 127, 7);
    hipLaunchKernelGGL(k_projadd, dim3(512), dim3(256), 0, stream,
                       xnbuf, wbuf, x, d_out);
  } else {
    for (int c = 0; c < 4; ++c) {
      hipLaunchKernelGGL(k_qkv, dim3(64, 6), dim3(256), 0, stream,
                         xnbuf, wbuf, qkvb, c * ROWS_CHUNK);
      hipLaunchKernelGGL(k_attn, dim3(NW_CHUNK * 8), dim3(256), 0, stream,
                         qkvb, xnbuf, c * NW_CHUNK, NW_CHUNK - 1, 5);
    }
    hipLaunchKernelGGL(k_proj, dim3(256, 2), dim3(256), 0, stream,
                       xnbuf, wbuf, x, d_out);
  }
}